// Round 9
// baseline (206.795 us; speedup 1.0000x reference)
//
#include <hip/hip_runtime.h>

#define N_NODES 50000
#define N_EDGES 800000
#define F 64
#define NTILES (N_NODES / 16)                  // 3125 (50000 = 3125*16 exactly)

#define BNODES 128                             // nodes per bucket
#define NB ((N_NODES + BNODES - 1) / BNODES)   // 391 buckets
#define EPB 3200                               // edges per bin_scatter block
#define SCAT_BLOCKS (N_EDGES / EPB)            // 250 (exact)

typedef __attribute__((ext_vector_type(8))) short short8;   // 8 bf16 (4 VGPRs)
typedef __attribute__((ext_vector_type(4))) float f32x4;    // MFMA accumulator

union frag16 { uint4 u; short8 s; };

// ---------------- bf16 helpers (storage-only; all math fp32/MFMA) ----------------

__device__ __forceinline__ float bf2f(unsigned short u) {
    union { unsigned int i; float f; } c; c.i = ((unsigned int)u) << 16; return c.f;
}
__device__ __forceinline__ unsigned short f2bf(float f) {   // round-nearest-even
    union { float f; unsigned int i; } c; c.f = f;
    unsigned int r = c.i + 0x7FFF + ((c.i >> 16) & 1);
    return (unsigned short)(r >> 16);
}

// ---------------- binned CSR build ----------------
// packed edge: src (bits 0-15) | dst_local (bits 16-22) | bucket (bits 23-31)

__global__ __launch_bounds__(256) void bin_count(const int* __restrict__ dst,
                                                 int* __restrict__ bcnt, int n) {
    __shared__ int lc[NB];
    for (int i = threadIdx.x; i < NB; i += 256) lc[i] = 0;
    __syncthreads();
    for (int e = blockIdx.x * 256 + threadIdx.x; e < n; e += gridDim.x * 256)
        atomicAdd(&lc[dst[e] >> 7], 1);
    __syncthreads();
    for (int i = threadIdx.x; i < NB; i += 256)
        if (lc[i]) atomicAdd(&bcnt[i], lc[i]);
}

__global__ __launch_bounds__(512) void bucket_scan(const int* __restrict__ bcnt,
                                                   int* __restrict__ bbase,
                                                   int* __restrict__ bcur) {
    __shared__ int s[512];
    int i = threadIdx.x;
    int v = (i < NB) ? bcnt[i] : 0;
    s[i] = v;
    __syncthreads();
    for (int off = 1; off < 512; off <<= 1) {
        int t = (i >= off) ? s[i - off] : 0;
        __syncthreads();
        s[i] += t;
        __syncthreads();
    }
    if (i < NB) { int b = s[i] - v; bbase[i] = b; bcur[i] = b; }
}

__global__ __launch_bounds__(512) void bin_scatter(const int* __restrict__ src,
                                                   const int* __restrict__ dst,
                                                   int* __restrict__ bcur,
                                                   unsigned int* __restrict__ binned, int n) {
    __shared__ int lcnt[NB];
    __shared__ int scan[512];
    __shared__ int gbase[NB];
    __shared__ int lcur[NB];
    __shared__ unsigned int staged[EPB];
    int tid = threadIdx.x;
    int e0 = blockIdx.x * EPB;
    int e1 = min(n, e0 + EPB);
    for (int i = tid; i < NB; i += 512) lcnt[i] = 0;
    __syncthreads();
    for (int i = e0 + tid; i < e1; i += 512)
        atomicAdd(&lcnt[dst[i] >> 7], 1);
    __syncthreads();
    int v = (tid < NB) ? lcnt[tid] : 0;
    scan[tid] = v;
    __syncthreads();
    for (int off = 1; off < 512; off <<= 1) {
        int t = (tid >= off) ? scan[tid - off] : 0;
        __syncthreads();
        scan[tid] += t;
        __syncthreads();
    }
    if (tid < NB) {
        int excl = scan[tid] - v;
        int resv = (v > 0) ? atomicAdd(&bcur[tid], v) : 0;
        gbase[tid] = resv - excl;
        lcur[tid] = excl;
    }
    __syncthreads();
    for (int i = e0 + tid; i < e1; i += 512) {
        int d = dst[i];
        int b = d >> 7;
        int dl = d & 127;
        int posl = atomicAdd(&lcur[b], 1);
        staged[posl] = (unsigned)src[i] | ((unsigned)dl << 16) | ((unsigned)b << 23);
    }
    __syncthreads();
    int cnt = e1 - e0;
    for (int i = tid; i < cnt; i += 512) {
        unsigned pk = staged[i];
        int b = pk >> 23;
        binned[gbase[b] + i] = pk;   // grouped by bucket -> mostly coalesced
    }
}

__global__ __launch_bounds__(256) void bucket_build(const unsigned int* __restrict__ binned,
                                                    const int* __restrict__ bbase,
                                                    const int* __restrict__ bcnt,
                                                    int* __restrict__ row_ptr,
                                                    unsigned short* __restrict__ csr16) {
    int b = blockIdx.x;
    int start = bbase[b];
    int cnt = bcnt[b];
    __shared__ int ncnt[BNODES];
    __shared__ int nofs[BNODES];
    __shared__ int ncur[BNODES];
    int tid = threadIdx.x;
    for (int i = tid; i < BNODES; i += 256) ncnt[i] = 0;
    __syncthreads();
    for (int i = tid; i < cnt; i += 256)
        atomicAdd(&ncnt[(binned[start + i] >> 16) & 127], 1);
    __syncthreads();
    if (tid < 128) nofs[tid] = ncnt[tid];
    __syncthreads();
    for (int off = 1; off < 128; off <<= 1) {
        int t = (tid >= off && tid < 128) ? nofs[tid - off] : 0;
        __syncthreads();
        if (tid < 128) nofs[tid] += t;
        __syncthreads();
    }
    if (tid < 128) {
        int excl = nofs[tid] - ncnt[tid];
        ncur[tid] = excl;
        int node = b * BNODES + tid;
        if (node <= N_NODES) row_ptr[node] = start + excl;   // node==N_NODES -> N_EDGES
    }
    __syncthreads();
    for (int i = tid; i < cnt; i += 256) {
        unsigned pk = binned[start + i];
        int dl = (pk >> 16) & 127;
        int pos = start + atomicAdd(&ncur[dl], 1);
        csr16[pos] = (unsigned short)(pk & 0xFFFF);
    }
}

// --------- prep: W transpose+cast (idx < 4*F*F) fused with x fp32->bf16 cvt ----------

__global__ __launch_bounds__(256) void prep_all(const float* __restrict__ W0,
                                                const float* __restrict__ W1,
                                                const float* __restrict__ W2,
                                                const float* __restrict__ W3,
                                                unsigned short* __restrict__ Wt,
                                                const float4* __restrict__ xin,
                                                ushort4* __restrict__ xout, int n4) {
    int idx = blockIdx.x * 256 + threadIdx.x;
    if (idx < 4 * F * F) {
        int m = idx >> 12;
        int e = idx & 4095;
        int n = e >> 6, k = e & 63;
        const float* W = (m == 0) ? W0 : (m == 1) ? W1 : (m == 2) ? W2 : W3;
        Wt[m * F * F + n * F + k] = f2bf(W[k * F + n]);
        return;
    }
    int i = idx - 4 * F * F;
    if (i >= n4) return;
    float4 v = xin[i];
    ushort4 o;
    o.x = f2bf(v.x); o.y = f2bf(v.y); o.z = f2bf(v.z); o.w = f2bf(v.w);
    xout[i] = o;
}

// ---------------- fused layer: aggregate (16 waves) -> LDS -> MFMA transform ---------
// Block = 1024 threads = 16 waves = one 16-node tile.
// Phase A: wave wv aggregates node base+wv (4 edge-groups x 16 lanes x ushort4,
//          4 chains) into LDS bf16 row saggh[wv] (padded to 72 ushorts).
// Phase B: waves 0..3 each compute jt=wv quarter of h = relu(x@Ws + agg@Wn + b).
//   layer1: store h as bf16 rows.  layer2: partial p=h.Wn3, q=h.Ws3 -> LDS -> reduce.

__global__ __launch_bounds__(1024, 8) void fused_layer(
        const ushort4* __restrict__ xh4, const int* __restrict__ row_ptr,
        const unsigned short* __restrict__ csr16,
        const uint4* __restrict__ Wst, const uint4* __restrict__ Wnt,
        const float* __restrict__ b,
        unsigned short* __restrict__ out_bf,
        const float* __restrict__ Ws3, const float* __restrict__ Wn3,
        float* __restrict__ pout, float* __restrict__ qout) {
    __shared__ unsigned short saggh[16][72];   // bf16 agg rows, +8 pad
    __shared__ float sp[4][16];
    __shared__ float sq[4][16];

    int wv   = threadIdx.x >> 6;
    int lane = threadIdx.x & 63;
    int base = blockIdx.x * 16;

    // ---- Phase A: aggregate node base+wv ----
    {
        int node = base + wv;
        int g   = lane >> 4;
        int sub = lane & 15;
        int beg = row_ptr[node], end = row_ptr[node + 1];
        float4 a0 = make_float4(0.f,0.f,0.f,0.f), a1 = a0, a2 = a0, a3 = a0;
        int i = beg + g;
        for (; i + 12 < end; i += 16) {
            int i0 = csr16[i], i1 = csr16[i+4], i2 = csr16[i+8], i3 = csr16[i+12];
            ushort4 v0 = xh4[i0 * 16 + sub];
            ushort4 v1 = xh4[i1 * 16 + sub];
            ushort4 v2 = xh4[i2 * 16 + sub];
            ushort4 v3 = xh4[i3 * 16 + sub];
            a0.x += bf2f(v0.x); a0.y += bf2f(v0.y); a0.z += bf2f(v0.z); a0.w += bf2f(v0.w);
            a1.x += bf2f(v1.x); a1.y += bf2f(v1.y); a1.z += bf2f(v1.z); a1.w += bf2f(v1.w);
            a2.x += bf2f(v2.x); a2.y += bf2f(v2.y); a2.z += bf2f(v2.z); a2.w += bf2f(v2.w);
            a3.x += bf2f(v3.x); a3.y += bf2f(v3.y); a3.z += bf2f(v3.z); a3.w += bf2f(v3.w);
        }
        for (; i < end; i += 4) {
            ushort4 v0 = xh4[csr16[i] * 16 + sub];
            a0.x += bf2f(v0.x); a0.y += bf2f(v0.y); a0.z += bf2f(v0.z); a0.w += bf2f(v0.w);
        }
        float4 s = make_float4(a0.x + a1.x + a2.x + a3.x,
                               a0.y + a1.y + a2.y + a3.y,
                               a0.z + a1.z + a2.z + a3.z,
                               a0.w + a1.w + a2.w + a3.w);
        #pragma unroll
        for (int off = 16; off <= 32; off <<= 1) {
            s.x += __shfl_xor(s.x, off);
            s.y += __shfl_xor(s.y, off);
            s.z += __shfl_xor(s.z, off);
            s.w += __shfl_xor(s.w, off);
        }
        if (g == 0) {
            int deg = end - beg;
            float inv = (deg > 0) ? (1.0f / (float)deg) : 0.f;
            ushort4 o;
            o.x = f2bf(s.x * inv); o.y = f2bf(s.y * inv);
            o.z = f2bf(s.z * inv); o.w = f2bf(s.w * inv);
            *(ushort4*)&saggh[wv][sub * 4] = o;
        }
    }
    __syncthreads();

    // ---- Phase B: waves 0..3, jt = wv ----
    if (wv < 4) {
        int jt = wv;
        int lo = lane & 15, hi = lane >> 4;
        int n = jt * 16 + lo;
        const uint4* xh16 = (const uint4*)xh4;

        frag16 ws[2], wn[2], ax[2], aa[2];
        #pragma unroll
        for (int kt = 0; kt < 2; ++kt) {
            ws[kt].u = Wst[n * 8 + kt * 4 + hi];
            wn[kt].u = Wnt[n * 8 + kt * 4 + hi];
            ax[kt].u = xh16[(base + lo) * 8 + kt * 4 + hi];
            aa[kt].u = *(const uint4*)&saggh[lo][kt * 32 + hi * 8];
        }

        float bias = b[n];
        f32x4 acc = f32x4{bias, bias, bias, bias};
        #pragma unroll
        for (int kt = 0; kt < 2; ++kt) {
            acc = __builtin_amdgcn_mfma_f32_16x16x32_bf16(ax[kt].s, ws[kt].s, acc, 0, 0, 0);
            acc = __builtin_amdgcn_mfma_f32_16x16x32_bf16(aa[kt].s, wn[kt].s, acc, 0, 0, 0);
        }

        if (out_bf) {
            #pragma unroll
            for (int r = 0; r < 4; ++r) {
                float h = fmaxf(acc[r], 0.f);
                out_bf[(base + hi * 4 + r) * F + n] = f2bf(h);
            }
        } else {
            float w3n = Wn3[n], w3s = Ws3[n];
            #pragma unroll
            for (int r = 0; r < 4; ++r) {
                float h = fmaxf(acc[r], 0.f);
                float pr = h * w3n;
                float qr = h * w3s;
                #pragma unroll
                for (int off = 1; off < 16; off <<= 1) {
                    pr += __shfl_xor(pr, off);
                    qr += __shfl_xor(qr, off);
                }
                if (lo == 0) {
                    sp[jt][hi * 4 + r] = pr;
                    sq[jt][hi * 4 + r] = qr;
                }
            }
        }
    }

    if (pout) {
        __syncthreads();
        if (threadIdx.x < 16) {
            int m = threadIdx.x;
            pout[base + m] = sp[0][m] + sp[1][m] + sp[2][m] + sp[3][m];
            qout[base + m] = sq[0][m] + sq[1][m] + sq[2][m] + sq[3][m];
        }
    }
}

// ---------------- final: out = q + mean_agg(p) + b3, 16 lanes per node ----------------

__global__ __launch_bounds__(256) void final_kernel(
        const int* __restrict__ row_ptr, const unsigned short* __restrict__ csr16,
        const float* __restrict__ p, const float* __restrict__ q,
        const float* __restrict__ b3, float* __restrict__ out, int n_nodes) {
    int grp = threadIdx.x >> 4;
    int ln  = threadIdx.x & 15;
    int node = blockIdx.x * 16 + grp;
    if (node >= n_nodes) return;
    int beg = row_ptr[node], end = row_ptr[node + 1];
    float s = 0.f;
    for (int i = beg + ln; i < end; i += 16) s += p[csr16[i]];
    #pragma unroll
    for (int off = 1; off < 16; off <<= 1) s += __shfl_xor(s, off);
    if (ln == 0) {
        int deg = end - beg;
        float inv = (deg > 0) ? (1.0f / (float)deg) : 0.f;
        out[node] = q[node] + s * inv + b3[0];
    }
}

// ---------------- launch ----------------

extern "C" void kernel_launch(void* const* d_in, const int* in_sizes, int n_in,
                              void* d_out, int out_size, void* d_ws, size_t ws_size,
                              hipStream_t stream) {
    const float* x   = (const float*)d_in[0];
    const int*   src = (const int*)d_in[1];
    const int*   dst = (const int*)d_in[2];
    const float* Ws1 = (const float*)d_in[3];
    const float* Wn1 = (const float*)d_in[4];
    const float* b1  = (const float*)d_in[5];
    const float* Ws2 = (const float*)d_in[6];
    const float* Wn2 = (const float*)d_in[7];
    const float* b2  = (const float*)d_in[8];
    const float* Ws3 = (const float*)d_in[9];
    const float* Wn3 = (const float*)d_in[10];
    const float* b3  = (const float*)d_in[11];
    float* out = (float*)d_out;

    char* ws = (char*)d_ws;
    size_t cur = 0;
    auto alloc = [&](size_t bytes) -> void* {
        void* p = ws + cur;
        cur += (bytes + 255) & ~(size_t)255;
        return p;
    };

    int*            bcnt     = (int*)  alloc(NB * sizeof(int));
    int*            bbase    = (int*)  alloc(NB * sizeof(int));
    int*            bcur     = (int*)  alloc(NB * sizeof(int));
    unsigned int*   binned   = (unsigned int*)alloc((size_t)N_EDGES * sizeof(unsigned int));
    int*            row_ptr  = (int*)  alloc((N_NODES + 1) * sizeof(int));
    unsigned short* csr16    = (unsigned short*)alloc(N_EDGES * sizeof(unsigned short));
    unsigned short* xh       = (unsigned short*)alloc((size_t)N_NODES * F * 2);  // bf16 x
    unsigned short* h1h      = (unsigned short*)alloc((size_t)N_NODES * F * 2);  // bf16 h1
    unsigned short* Wt       = (unsigned short*)alloc(4 * F * F * 2);            // bf16 W^T x4
    float*          p        = (float*)alloc(N_NODES * sizeof(float));
    float*          q        = (float*)alloc(N_NODES * sizeof(float));

    unsigned short* Wst1 = Wt;
    unsigned short* Wnt1 = Wt + F * F;
    unsigned short* Wst2 = Wt + 2 * F * F;
    unsigned short* Wnt2 = Wt + 3 * F * F;

    // binned CSR build
    (void)hipMemsetAsync(bcnt, 0, NB * sizeof(int), stream);
    bin_count<<<256, 256, 0, stream>>>(dst, bcnt, N_EDGES);
    bucket_scan<<<1, 512, 0, stream>>>(bcnt, bbase, bcur);
    bin_scatter<<<SCAT_BLOCKS, 512, 0, stream>>>(src, dst, bcur, binned, N_EDGES);
    bucket_build<<<NB, 256, 0, stream>>>(binned, bbase, bcnt, row_ptr, csr16);

    // weight transpose+cast fused with x -> bf16
    prep_all<<<(4 * F * F + N_NODES * 16 + 255) / 256, 256, 0, stream>>>(
        Ws1, Wn1, Ws2, Wn2, Wt, (const float4*)x, (ushort4*)xh, N_NODES * 16);

    // layer 1 (fused aggregate + transform)
    fused_layer<<<NTILES, 1024, 0, stream>>>(
        (const ushort4*)xh, row_ptr, csr16,
        (const uint4*)Wst1, (const uint4*)Wnt1, b1,
        h1h, nullptr, nullptr, nullptr, nullptr);
    // layer 2 (fused aggregate + transform + layer-3 projection)
    fused_layer<<<NTILES, 1024, 0, stream>>>(
        (const ushort4*)h1h, row_ptr, csr16,
        (const uint4*)Wst2, (const uint4*)Wnt2, b2,
        nullptr, Ws3, Wn3, p, q);
    // layer 3: aggregate scalars
    final_kernel<<<(N_NODES + 15) / 16, 256, 0, stream>>>(row_ptr, csr16, p, q, b3, out, N_NODES);
}

// Round 10
// 194.068 us; speedup vs baseline: 1.0656x; 1.0656x over previous
//
#include <hip/hip_runtime.h>

#define N_NODES 50000
#define N_EDGES 800000
#define F 64
#define NTILES (N_NODES / 16)                  // 3125 (50000 = 3125*16 exactly)

#define BNODES 128                             // nodes per bucket
#define NB ((N_NODES + BNODES - 1) / BNODES)   // 391 buckets
#define EPB 3200                               // edges per bin_scatter block
#define SCAT_BLOCKS (N_EDGES / EPB)            // 250 (exact)

typedef __attribute__((ext_vector_type(8))) short short8;   // 8 bf16 (4 VGPRs)
typedef __attribute__((ext_vector_type(4))) float f32x4;    // MFMA accumulator

union frag16 { uint4 u; short8 s; };

// ---------------- bf16 helpers (storage-only; all math fp32/MFMA) ----------------

__device__ __forceinline__ float bf2f(unsigned short u) {
    union { unsigned int i; float f; } c; c.i = ((unsigned int)u) << 16; return c.f;
}
__device__ __forceinline__ float bflo(unsigned int u) {
    union { unsigned int i; float f; } c; c.i = u << 16; return c.f;
}
__device__ __forceinline__ float bfhi(unsigned int u) {
    union { unsigned int i; float f; } c; c.i = u & 0xFFFF0000u; return c.f;
}
__device__ __forceinline__ unsigned short f2bf(float f) {   // round-nearest-even
    union { float f; unsigned int i; } c; c.f = f;
    unsigned int r = c.i + 0x7FFF + ((c.i >> 16) & 1);
    return (unsigned short)(r >> 16);
}

// ---------------- binned CSR build ----------------
// packed edge: src (bits 0-15) | dst_local (bits 16-22) | bucket (bits 23-31)

__global__ __launch_bounds__(256) void bin_count(const int* __restrict__ dst,
                                                 int* __restrict__ bcnt, int n) {
    __shared__ int lc[NB];
    for (int i = threadIdx.x; i < NB; i += 256) lc[i] = 0;
    __syncthreads();
    for (int e = blockIdx.x * 256 + threadIdx.x; e < n; e += gridDim.x * 256)
        atomicAdd(&lc[dst[e] >> 7], 1);
    __syncthreads();
    for (int i = threadIdx.x; i < NB; i += 256)
        if (lc[i]) atomicAdd(&bcnt[i], lc[i]);
}

__global__ __launch_bounds__(512) void bucket_scan(const int* __restrict__ bcnt,
                                                   int* __restrict__ bbase,
                                                   int* __restrict__ bcur) {
    __shared__ int s[512];
    int i = threadIdx.x;
    int v = (i < NB) ? bcnt[i] : 0;
    s[i] = v;
    __syncthreads();
    for (int off = 1; off < 512; off <<= 1) {
        int t = (i >= off) ? s[i - off] : 0;
        __syncthreads();
        s[i] += t;
        __syncthreads();
    }
    if (i < NB) { int b = s[i] - v; bbase[i] = b; bcur[i] = b; }
}

__global__ __launch_bounds__(512) void bin_scatter(const int* __restrict__ src,
                                                   const int* __restrict__ dst,
                                                   int* __restrict__ bcur,
                                                   unsigned int* __restrict__ binned, int n) {
    __shared__ int lcnt[NB];
    __shared__ int scan[512];
    __shared__ int gbase[NB];
    __shared__ int lcur[NB];
    __shared__ unsigned int staged[EPB];
    int tid = threadIdx.x;
    int e0 = blockIdx.x * EPB;
    int e1 = min(n, e0 + EPB);
    for (int i = tid; i < NB; i += 512) lcnt[i] = 0;
    __syncthreads();
    for (int i = e0 + tid; i < e1; i += 512)
        atomicAdd(&lcnt[dst[i] >> 7], 1);
    __syncthreads();
    int v = (tid < NB) ? lcnt[tid] : 0;
    scan[tid] = v;
    __syncthreads();
    for (int off = 1; off < 512; off <<= 1) {
        int t = (tid >= off) ? scan[tid - off] : 0;
        __syncthreads();
        scan[tid] += t;
        __syncthreads();
    }
    if (tid < NB) {
        int excl = scan[tid] - v;
        int resv = (v > 0) ? atomicAdd(&bcur[tid], v) : 0;
        gbase[tid] = resv - excl;
        lcur[tid] = excl;
    }
    __syncthreads();
    for (int i = e0 + tid; i < e1; i += 512) {
        int d = dst[i];
        int b = d >> 7;
        int dl = d & 127;
        int posl = atomicAdd(&lcur[b], 1);
        staged[posl] = (unsigned)src[i] | ((unsigned)dl << 16) | ((unsigned)b << 23);
    }
    __syncthreads();
    int cnt = e1 - e0;
    for (int i = tid; i < cnt; i += 512) {
        unsigned pk = staged[i];
        int b = pk >> 23;
        binned[gbase[b] + i] = pk;   // grouped by bucket -> mostly coalesced
    }
}

__global__ __launch_bounds__(256) void bucket_build(const unsigned int* __restrict__ binned,
                                                    const int* __restrict__ bbase,
                                                    const int* __restrict__ bcnt,
                                                    int* __restrict__ row_ptr,
                                                    unsigned short* __restrict__ csr16) {
    int b = blockIdx.x;
    int start = bbase[b];
    int cnt = bcnt[b];
    __shared__ int ncnt[BNODES];
    __shared__ int nofs[BNODES];
    __shared__ int ncur[BNODES];
    int tid = threadIdx.x;
    for (int i = tid; i < BNODES; i += 256) ncnt[i] = 0;
    __syncthreads();
    for (int i = tid; i < cnt; i += 256)
        atomicAdd(&ncnt[(binned[start + i] >> 16) & 127], 1);
    __syncthreads();
    if (tid < 128) nofs[tid] = ncnt[tid];
    __syncthreads();
    for (int off = 1; off < 128; off <<= 1) {
        int t = (tid >= off && tid < 128) ? nofs[tid - off] : 0;
        __syncthreads();
        if (tid < 128) nofs[tid] += t;
        __syncthreads();
    }
    if (tid < 128) {
        int excl = nofs[tid] - ncnt[tid];
        ncur[tid] = excl;
        int node = b * BNODES + tid;
        if (node <= N_NODES) row_ptr[node] = start + excl;   // node==N_NODES -> N_EDGES
    }
    __syncthreads();
    for (int i = tid; i < cnt; i += 256) {
        unsigned pk = binned[start + i];
        int dl = (pk >> 16) & 127;
        int pos = start + atomicAdd(&ncur[dl], 1);
        csr16[pos] = (unsigned short)(pk & 0xFFFF);
    }
}

// --------- prep: W transpose+cast (idx < 4*F*F) fused with x fp32->bf16 cvt ----------

__global__ __launch_bounds__(256) void prep_all(const float* __restrict__ W0,
                                                const float* __restrict__ W1,
                                                const float* __restrict__ W2,
                                                const float* __restrict__ W3,
                                                unsigned short* __restrict__ Wt,
                                                const float4* __restrict__ xin,
                                                ushort4* __restrict__ xout, int n4) {
    int idx = blockIdx.x * 256 + threadIdx.x;
    if (idx < 4 * F * F) {
        int m = idx >> 12;
        int e = idx & 4095;
        int n = e >> 6, k = e & 63;
        const float* W = (m == 0) ? W0 : (m == 1) ? W1 : (m == 2) ? W2 : W3;
        Wt[m * F * F + n * F + k] = f2bf(W[k * F + n]);
        return;
    }
    int i = idx - 4 * F * F;
    if (i >= n4) return;
    float4 v = xin[i];
    ushort4 o;
    o.x = f2bf(v.x); o.y = f2bf(v.y); o.z = f2bf(v.z); o.w = f2bf(v.w);
    xout[i] = o;
}

// ------------- aggregation: wave/node, 8 groups x 8 lanes x ushort8 (16B), 2 chains --
// One wave instruction gathers 8 independent 128B rows (1 KB): max bytes per
// outstanding request. deg~16 -> whole node in 2 loads.

__global__ __launch_bounds__(256) void aggregate_kernel(
        const uint4* __restrict__ xh8, const int* __restrict__ row_ptr,
        const unsigned short* __restrict__ csr16, uint4* __restrict__ aggh8, int n_nodes) {
    int wave = threadIdx.x >> 6;
    int lane = threadIdx.x & 63;
    int node = blockIdx.x * 4 + wave;
    if (node >= n_nodes) return;
    int g   = lane >> 3;    // edge group 0..7
    int sub = lane & 7;     // ushort8 (8 feats, 16B) within the 64-feat row
    int beg = row_ptr[node], end = row_ptr[node + 1];
    float a0[8], a1[8];
    #pragma unroll
    for (int j = 0; j < 8; ++j) { a0[j] = 0.f; a1[j] = 0.f; }
    int i = beg + g;
    for (; i + 8 < end; i += 16) {   // 2 chains x 8 groups = 16 edges in flight
        int i0 = csr16[i];
        int i1 = csr16[i + 8];
        uint4 v0 = xh8[i0 * 8 + sub];
        uint4 v1 = xh8[i1 * 8 + sub];
        a0[0] += bflo(v0.x); a0[1] += bfhi(v0.x); a0[2] += bflo(v0.y); a0[3] += bfhi(v0.y);
        a0[4] += bflo(v0.z); a0[5] += bfhi(v0.z); a0[6] += bflo(v0.w); a0[7] += bfhi(v0.w);
        a1[0] += bflo(v1.x); a1[1] += bfhi(v1.x); a1[2] += bflo(v1.y); a1[3] += bfhi(v1.y);
        a1[4] += bflo(v1.z); a1[5] += bfhi(v1.z); a1[6] += bflo(v1.w); a1[7] += bfhi(v1.w);
    }
    if (i < end) {
        uint4 v0 = xh8[csr16[i] * 8 + sub];
        a0[0] += bflo(v0.x); a0[1] += bfhi(v0.x); a0[2] += bflo(v0.y); a0[3] += bfhi(v0.y);
        a0[4] += bflo(v0.z); a0[5] += bfhi(v0.z); a0[6] += bflo(v0.w); a0[7] += bfhi(v0.w);
    }
    float s[8];
    #pragma unroll
    for (int j = 0; j < 8; ++j) s[j] = a0[j] + a1[j];
    #pragma unroll
    for (int off = 8; off <= 32; off <<= 1)
        #pragma unroll
        for (int j = 0; j < 8; ++j)
            s[j] += __shfl_xor(s[j], off);
    if (g == 0) {
        int deg = end - beg;
        float inv = (deg > 0) ? (1.0f / (float)deg) : 0.f;
        unsigned short o[8];
        #pragma unroll
        for (int j = 0; j < 8; ++j) o[j] = f2bf(s[j] * inv);
        uint4 pk;
        pk.x = (unsigned)o[0] | ((unsigned)o[1] << 16);
        pk.y = (unsigned)o[2] | ((unsigned)o[3] << 16);
        pk.z = (unsigned)o[4] | ((unsigned)o[5] << 16);
        pk.w = (unsigned)o[6] | ((unsigned)o[7] << 16);
        aggh8[node * 8 + sub] = pk;
    }
}

// ---------------- MFMA transform: h = relu(x@Ws + agg@Wn + b) ------------------------
// One wave per 16-node m-tile, no LDS (R7 known-good).

__global__ __launch_bounds__(256) void mfma_transform(
        const uint4* __restrict__ xh, const uint4* __restrict__ aggh,
        const uint4* __restrict__ Wst, const uint4* __restrict__ Wnt,
        const float* __restrict__ b,
        unsigned short* __restrict__ out_bf,
        const float* __restrict__ Ws3, const float* __restrict__ Wn3,
        float* __restrict__ pout, float* __restrict__ qout, int ntiles) {
    int wv   = threadIdx.x >> 6;
    int lane = threadIdx.x & 63;
    int tile = blockIdx.x * 4 + wv;
    if (tile >= ntiles) return;
    int lo = lane & 15, hi = lane >> 4;

    frag16 ws[2][4], wn[2][4];
    #pragma unroll
    for (int kt = 0; kt < 2; ++kt)
        #pragma unroll
        for (int jt = 0; jt < 4; ++jt) {
            int n = jt * 16 + lo;
            ws[kt][jt].u = Wst[n * 8 + kt * 4 + hi];
            wn[kt][jt].u = Wnt[n * 8 + kt * 4 + hi];
        }

    float bias_s[4];
    #pragma unroll
    for (int jt = 0; jt < 4; ++jt) bias_s[jt] = b[jt * 16 + lo];
    float w3n_s[4], w3s_s[4];
    if (pout) {
        #pragma unroll
        for (int jt = 0; jt < 4; ++jt) {
            w3n_s[jt] = Wn3[jt * 16 + lo];
            w3s_s[jt] = Ws3[jt * 16 + lo];
        }
    }

    int base = tile * 16;
    int node = base + lo;

    frag16 ax[2], aa[2];
    #pragma unroll
    for (int kt = 0; kt < 2; ++kt) {
        ax[kt].u = xh[node * 8 + kt * 4 + hi];
        aa[kt].u = aggh[node * 8 + kt * 4 + hi];
    }

    f32x4 acc[4];
    #pragma unroll
    for (int jt = 0; jt < 4; ++jt)
        acc[jt] = f32x4{bias_s[jt], bias_s[jt], bias_s[jt], bias_s[jt]};

    #pragma unroll
    for (int kt = 0; kt < 2; ++kt)
        #pragma unroll
        for (int jt = 0; jt < 4; ++jt) {
            acc[jt] = __builtin_amdgcn_mfma_f32_16x16x32_bf16(ax[kt].s, ws[kt][jt].s, acc[jt], 0, 0, 0);
            acc[jt] = __builtin_amdgcn_mfma_f32_16x16x32_bf16(aa[kt].s, wn[kt][jt].s, acc[jt], 0, 0, 0);
        }

    if (out_bf) {
        #pragma unroll
        for (int jt = 0; jt < 4; ++jt)
            #pragma unroll
            for (int r = 0; r < 4; ++r) {
                float h = fmaxf(acc[jt][r], 0.f);
                out_bf[(base + hi * 4 + r) * F + jt * 16 + lo] = f2bf(h);
            }
    } else {
        #pragma unroll
        for (int r = 0; r < 4; ++r) {
            float pr = 0.f, qr = 0.f;
            #pragma unroll
            for (int jt = 0; jt < 4; ++jt) {
                float h = fmaxf(acc[jt][r], 0.f);
                pr += h * w3n_s[jt];
                qr += h * w3s_s[jt];
            }
            #pragma unroll
            for (int off = 1; off < 16; off <<= 1) {
                pr += __shfl_xor(pr, off);
                qr += __shfl_xor(qr, off);
            }
            if (lo == 0) {
                pout[base + hi * 4 + r] = pr;
                qout[base + hi * 4 + r] = qr;
            }
        }
    }
}

// ---------------- final: out = q + mean_agg(p) + b3, 16 lanes per node ----------------

__global__ __launch_bounds__(256) void final_kernel(
        const int* __restrict__ row_ptr, const unsigned short* __restrict__ csr16,
        const float* __restrict__ p, const float* __restrict__ q,
        const float* __restrict__ b3, float* __restrict__ out, int n_nodes) {
    int grp = threadIdx.x >> 4;
    int ln  = threadIdx.x & 15;
    int node = blockIdx.x * 16 + grp;
    if (node >= n_nodes) return;
    int beg = row_ptr[node], end = row_ptr[node + 1];
    float s = 0.f;
    for (int i = beg + ln; i < end; i += 16) s += p[csr16[i]];
    #pragma unroll
    for (int off = 1; off < 16; off <<= 1) s += __shfl_xor(s, off);
    if (ln == 0) {
        int deg = end - beg;
        float inv = (deg > 0) ? (1.0f / (float)deg) : 0.f;
        out[node] = q[node] + s * inv + b3[0];
    }
}

// ---------------- launch ----------------

extern "C" void kernel_launch(void* const* d_in, const int* in_sizes, int n_in,
                              void* d_out, int out_size, void* d_ws, size_t ws_size,
                              hipStream_t stream) {
    const float* x   = (const float*)d_in[0];
    const int*   src = (const int*)d_in[1];
    const int*   dst = (const int*)d_in[2];
    const float* Ws1 = (const float*)d_in[3];
    const float* Wn1 = (const float*)d_in[4];
    const float* b1  = (const float*)d_in[5];
    const float* Ws2 = (const float*)d_in[6];
    const float* Wn2 = (const float*)d_in[7];
    const float* b2  = (const float*)d_in[8];
    const float* Ws3 = (const float*)d_in[9];
    const float* Wn3 = (const float*)d_in[10];
    const float* b3  = (const float*)d_in[11];
    float* out = (float*)d_out;

    char* ws = (char*)d_ws;
    size_t cur = 0;
    auto alloc = [&](size_t bytes) -> void* {
        void* p = ws + cur;
        cur += (bytes + 255) & ~(size_t)255;
        return p;
    };

    int*            bcnt     = (int*)  alloc(NB * sizeof(int));
    int*            bbase    = (int*)  alloc(NB * sizeof(int));
    int*            bcur     = (int*)  alloc(NB * sizeof(int));
    unsigned int*   binned   = (unsigned int*)alloc((size_t)N_EDGES * sizeof(unsigned int));
    int*            row_ptr  = (int*)  alloc((N_NODES + 1) * sizeof(int));
    unsigned short* csr16    = (unsigned short*)alloc(N_EDGES * sizeof(unsigned short));
    unsigned short* xh       = (unsigned short*)alloc((size_t)N_NODES * F * 2);  // bf16 x
    unsigned short* h1h      = (unsigned short*)alloc((size_t)N_NODES * F * 2);  // bf16 h1
    unsigned short* aggh     = (unsigned short*)alloc((size_t)N_NODES * F * 2);  // bf16 agg
    unsigned short* Wt       = (unsigned short*)alloc(4 * F * F * 2);            // bf16 W^T x4
    float*          p        = (float*)alloc(N_NODES * sizeof(float));
    float*          q        = (float*)alloc(N_NODES * sizeof(float));

    unsigned short* Wst1 = Wt;
    unsigned short* Wnt1 = Wt + F * F;
    unsigned short* Wst2 = Wt + 2 * F * F;
    unsigned short* Wnt2 = Wt + 3 * F * F;

    // binned CSR build
    (void)hipMemsetAsync(bcnt, 0, NB * sizeof(int), stream);
    bin_count<<<256, 256, 0, stream>>>(dst, bcnt, N_EDGES);
    bucket_scan<<<1, 512, 0, stream>>>(bcnt, bbase, bcur);
    bin_scatter<<<SCAT_BLOCKS, 512, 0, stream>>>(src, dst, bcur, binned, N_EDGES);
    bucket_build<<<NB, 256, 0, stream>>>(binned, bbase, bcnt, row_ptr, csr16);

    // weight transpose+cast fused with x -> bf16
    prep_all<<<(4 * F * F + N_NODES * 16 + 255) / 256, 256, 0, stream>>>(
        Ws1, Wn1, Ws2, Wn2, Wt, (const float4*)x, (ushort4*)xh, N_NODES * 16);

    int agg_grid = (N_NODES + 3) / 4;
    int tf_grid  = (NTILES + 3) / 4;   // 782

    // layer 1
    aggregate_kernel<<<agg_grid, 256, 0, stream>>>(
        (const uint4*)xh, row_ptr, csr16, (uint4*)aggh, N_NODES);
    mfma_transform<<<tf_grid, 256, 0, stream>>>(
        (const uint4*)xh, (const uint4*)aggh, (const uint4*)Wst1, (const uint4*)Wnt1,
        b1, h1h, nullptr, nullptr, nullptr, nullptr, NTILES);
    // layer 2 (+ fused layer-3 projection)
    aggregate_kernel<<<agg_grid, 256, 0, stream>>>(
        (const uint4*)h1h, row_ptr, csr16, (uint4*)aggh, N_NODES);
    mfma_transform<<<tf_grid, 256, 0, stream>>>(
        (const uint4*)h1h, (const uint4*)aggh, (const uint4*)Wst2, (const uint4*)Wnt2,
        b2, nullptr, Ws3, Wn3, p, q, NTILES);
    // layer 3: aggregate scalars
    final_kernel<<<(N_NODES + 15) / 16, 256, 0, stream>>>(row_ptr, csr16, p, q, b3, out, N_NODES);
}

// Round 11
// 179.453 us; speedup vs baseline: 1.1524x; 1.0814x over previous
//
#include <hip/hip_runtime.h>

#define N_NODES 50000
#define N_EDGES 800000
#define F 64
#define NTILES (N_NODES / 16)                  // 3125

#define BNODES 128                             // nodes per bucket
#define NB ((N_NODES + BNODES - 1) / BNODES)   // 391 buckets
#define BCAP 2560                              // bucket capacity (mean 2046, +25% slack)
#define EPB 3200                               // edges per scatter block
#define SCAT_BLOCKS (N_EDGES / EPB)            // 250 (exact)
#define PREP_ELEMS (4 * F * F + N_NODES * 16)  // W entries + float4 groups
#define PREP_BLOCKS ((PREP_ELEMS + 511) / 512)

typedef __attribute__((ext_vector_type(8))) short short8;   // 8 bf16 (4 VGPRs)
typedef __attribute__((ext_vector_type(4))) float f32x4;    // MFMA accumulator

union frag16 { uint4 u; short8 s; };

// ---------------- bf16 helpers (storage-only; all math fp32/MFMA) ----------------

__device__ __forceinline__ float bflo(unsigned int u) {
    union { unsigned int i; float f; } c; c.i = u << 16; return c.f;
}
__device__ __forceinline__ float bfhi(unsigned int u) {
    union { unsigned int i; float f; } c; c.i = u & 0xFFFF0000u; return c.f;
}
__device__ __forceinline__ unsigned short f2bf(float f) {   // round-nearest-even
    union { float f; unsigned int i; } c; c.f = f;
    unsigned int r = c.i + 0x7FFF + ((c.i >> 16) & 1);
    return (unsigned short)(r >> 16);
}

// -------- fused: single-pass LDS-staged bucket scatter  +  W/x bf16 prep -------------
// scatter blocks (blockIdx < SCAT_BLOCKS): stage EPB edges, group by bucket in LDS,
// reserve [b*BCAP + atomicAdd(bcur[b], v)] ranges, write grouped.
// prep blocks: W fp32[k][n] -> bf16 W^T[n][k] (4 mats), then x fp32 -> bf16.
// packed edge: src (bits 0-15) | dst_local (bits 16-22) | bucket (bits 23-31)

__global__ __launch_bounds__(512) void scatter_prep(
        const int* __restrict__ src, const int* __restrict__ dst,
        int* __restrict__ bcur, unsigned int* __restrict__ binned,
        const float* __restrict__ W0, const float* __restrict__ W1,
        const float* __restrict__ W2, const float* __restrict__ W3,
        unsigned short* __restrict__ Wt,
        const float4* __restrict__ xin, ushort4* __restrict__ xout) {
    if (blockIdx.x >= SCAT_BLOCKS) {
        int idx = (blockIdx.x - SCAT_BLOCKS) * 512 + threadIdx.x;
        if (idx < 4 * F * F) {
            int m = idx >> 12;
            int e = idx & 4095;
            int n = e >> 6, k = e & 63;
            const float* W = (m == 0) ? W0 : (m == 1) ? W1 : (m == 2) ? W2 : W3;
            Wt[m * F * F + n * F + k] = f2bf(W[k * F + n]);
            return;
        }
        int i = idx - 4 * F * F;
        if (i >= N_NODES * 16) return;
        float4 v = xin[i];
        ushort4 o;
        o.x = f2bf(v.x); o.y = f2bf(v.y); o.z = f2bf(v.z); o.w = f2bf(v.w);
        xout[i] = o;
        return;
    }

    __shared__ int lcnt[NB];
    __shared__ int scan[512];
    __shared__ int gbase[NB];
    __shared__ int lcur[NB];
    __shared__ unsigned int staged[EPB];
    int tid = threadIdx.x;
    int e0 = blockIdx.x * EPB;
    int e1 = min(N_EDGES, e0 + EPB);
    for (int i = tid; i < NB; i += 512) lcnt[i] = 0;
    __syncthreads();
    for (int i = e0 + tid; i < e1; i += 512)
        atomicAdd(&lcnt[dst[i] >> 7], 1);
    __syncthreads();
    int v = (tid < NB) ? lcnt[tid] : 0;
    scan[tid] = v;
    __syncthreads();
    for (int off = 1; off < 512; off <<= 1) {
        int t = (tid >= off) ? scan[tid - off] : 0;
        __syncthreads();
        scan[tid] += t;
        __syncthreads();
    }
    if (tid < NB) {
        int excl = scan[tid] - v;
        int resv = (v > 0) ? atomicAdd(&bcur[tid], v) : 0;
        gbase[tid] = tid * BCAP + resv - excl;
        lcur[tid] = excl;
    }
    __syncthreads();
    for (int i = e0 + tid; i < e1; i += 512) {
        int d = dst[i];
        int b = d >> 7;
        int dl = d & 127;
        int posl = atomicAdd(&lcur[b], 1);
        staged[posl] = (unsigned)src[i] | ((unsigned)dl << 16) | ((unsigned)b << 23);
    }
    __syncthreads();
    int cnt = e1 - e0;
    for (int i = tid; i < cnt; i += 512) {
        unsigned pk = staged[i];
        int b = pk >> 23;
        binned[gbase[b] + i] = pk;   // grouped by bucket -> mostly coalesced
    }
}

// ---- bucket_build: per bucket, node counts + local scan -> row_beg/degs/csr16 -------

__global__ __launch_bounds__(256) void bucket_build(const unsigned int* __restrict__ binned,
                                                    const int* __restrict__ bcur,
                                                    int* __restrict__ row_beg,
                                                    unsigned short* __restrict__ degs,
                                                    unsigned short* __restrict__ csr16) {
    int b = blockIdx.x;
    int start = b * BCAP;
    int cnt = bcur[b];
    __shared__ int ncnt[BNODES];
    __shared__ int nofs[BNODES];
    __shared__ int ncur[BNODES];
    int tid = threadIdx.x;
    for (int i = tid; i < BNODES; i += 256) ncnt[i] = 0;
    __syncthreads();
    for (int i = tid; i < cnt; i += 256)
        atomicAdd(&ncnt[(binned[start + i] >> 16) & 127], 1);
    __syncthreads();
    if (tid < 128) nofs[tid] = ncnt[tid];
    __syncthreads();
    for (int off = 1; off < 128; off <<= 1) {
        int t = (tid >= off && tid < 128) ? nofs[tid - off] : 0;
        __syncthreads();
        if (tid < 128) nofs[tid] += t;
        __syncthreads();
    }
    if (tid < 128) {
        int excl = nofs[tid] - ncnt[tid];
        ncur[tid] = excl;
        int node = b * BNODES + tid;
        row_beg[node] = start + excl;
        degs[node] = (unsigned short)ncnt[tid];
    }
    __syncthreads();
    for (int i = tid; i < cnt; i += 256) {
        unsigned pk = binned[start + i];
        int dl = (pk >> 16) & 127;
        int pos = start + atomicAdd(&ncur[dl], 1);
        csr16[pos] = (unsigned short)(pk & 0xFFFF);
    }
}

// ------------- aggregation: wave/node, 8 groups x 8 lanes x ushort8 (16B), 2 chains --

__global__ __launch_bounds__(256) void aggregate_kernel(
        const uint4* __restrict__ xh8, const int* __restrict__ row_beg,
        const unsigned short* __restrict__ degs,
        const unsigned short* __restrict__ csr16, uint4* __restrict__ aggh8, int n_nodes) {
    int wave = threadIdx.x >> 6;
    int lane = threadIdx.x & 63;
    int node = blockIdx.x * 4 + wave;
    if (node >= n_nodes) return;
    int g   = lane >> 3;    // edge group 0..7
    int sub = lane & 7;     // ushort8 (8 feats, 16B) within the 64-feat row
    int beg = row_beg[node];
    int deg = degs[node];
    int end = beg + deg;
    float a0[8], a1[8];
    #pragma unroll
    for (int j = 0; j < 8; ++j) { a0[j] = 0.f; a1[j] = 0.f; }
    int i = beg + g;
    for (; i + 8 < end; i += 16) {   // 2 chains x 8 groups = 16 edges in flight
        int i0 = csr16[i];
        int i1 = csr16[i + 8];
        uint4 v0 = xh8[i0 * 8 + sub];
        uint4 v1 = xh8[i1 * 8 + sub];
        a0[0] += bflo(v0.x); a0[1] += bfhi(v0.x); a0[2] += bflo(v0.y); a0[3] += bfhi(v0.y);
        a0[4] += bflo(v0.z); a0[5] += bfhi(v0.z); a0[6] += bflo(v0.w); a0[7] += bfhi(v0.w);
        a1[0] += bflo(v1.x); a1[1] += bfhi(v1.x); a1[2] += bflo(v1.y); a1[3] += bfhi(v1.y);
        a1[4] += bflo(v1.z); a1[5] += bfhi(v1.z); a1[6] += bflo(v1.w); a1[7] += bfhi(v1.w);
    }
    if (i < end) {
        uint4 v0 = xh8[csr16[i] * 8 + sub];
        a0[0] += bflo(v0.x); a0[1] += bfhi(v0.x); a0[2] += bflo(v0.y); a0[3] += bfhi(v0.y);
        a0[4] += bflo(v0.z); a0[5] += bfhi(v0.z); a0[6] += bflo(v0.w); a0[7] += bfhi(v0.w);
    }
    float s[8];
    #pragma unroll
    for (int j = 0; j < 8; ++j) s[j] = a0[j] + a1[j];
    #pragma unroll
    for (int off = 8; off <= 32; off <<= 1)
        #pragma unroll
        for (int j = 0; j < 8; ++j)
            s[j] += __shfl_xor(s[j], off);
    if (g == 0) {
        float inv = (deg > 0) ? (1.0f / (float)deg) : 0.f;
        unsigned short o[8];
        #pragma unroll
        for (int j = 0; j < 8; ++j) o[j] = f2bf(s[j] * inv);
        uint4 pk;
        pk.x = (unsigned)o[0] | ((unsigned)o[1] << 16);
        pk.y = (unsigned)o[2] | ((unsigned)o[3] << 16);
        pk.z = (unsigned)o[4] | ((unsigned)o[5] << 16);
        pk.w = (unsigned)o[6] | ((unsigned)o[7] << 16);
        aggh8[node * 8 + sub] = pk;
    }
}

// ---------------- MFMA transform: h = relu(x@Ws + agg@Wn + b) ------------------------
// One wave per 16-node m-tile, no LDS (R7/R10 known-good).

__global__ __launch_bounds__(256) void mfma_transform(
        const uint4* __restrict__ xh, const uint4* __restrict__ aggh,
        const uint4* __restrict__ Wst, const uint4* __restrict__ Wnt,
        const float* __restrict__ b,
        unsigned short* __restrict__ out_bf,
        const float* __restrict__ Ws3, const float* __restrict__ Wn3,
        float* __restrict__ pout, float* __restrict__ qout, int ntiles) {
    int wv   = threadIdx.x >> 6;
    int lane = threadIdx.x & 63;
    int tile = blockIdx.x * 4 + wv;
    if (tile >= ntiles) return;
    int lo = lane & 15, hi = lane >> 4;

    frag16 ws[2][4], wn[2][4];
    #pragma unroll
    for (int kt = 0; kt < 2; ++kt)
        #pragma unroll
        for (int jt = 0; jt < 4; ++jt) {
            int n = jt * 16 + lo;
            ws[kt][jt].u = Wst[n * 8 + kt * 4 + hi];
            wn[kt][jt].u = Wnt[n * 8 + kt * 4 + hi];
        }

    float bias_s[4];
    #pragma unroll
    for (int jt = 0; jt < 4; ++jt) bias_s[jt] = b[jt * 16 + lo];
    float w3n_s[4], w3s_s[4];
    if (pout) {
        #pragma unroll
        for (int jt = 0; jt < 4; ++jt) {
            w3n_s[jt] = Wn3[jt * 16 + lo];
            w3s_s[jt] = Ws3[jt * 16 + lo];
        }
    }

    int base = tile * 16;
    int node = base + lo;

    frag16 ax[2], aa[2];
    #pragma unroll
    for (int kt = 0; kt < 2; ++kt) {
        ax[kt].u = xh[node * 8 + kt * 4 + hi];
        aa[kt].u = aggh[node * 8 + kt * 4 + hi];
    }

    f32x4 acc[4];
    #pragma unroll
    for (int jt = 0; jt < 4; ++jt)
        acc[jt] = f32x4{bias_s[jt], bias_s[jt], bias_s[jt], bias_s[jt]};

    #pragma unroll
    for (int kt = 0; kt < 2; ++kt)
        #pragma unroll
        for (int jt = 0; jt < 4; ++jt) {
            acc[jt] = __builtin_amdgcn_mfma_f32_16x16x32_bf16(ax[kt].s, ws[kt][jt].s, acc[jt], 0, 0, 0);
            acc[jt] = __builtin_amdgcn_mfma_f32_16x16x32_bf16(aa[kt].s, wn[kt][jt].s, acc[jt], 0, 0, 0);
        }

    if (out_bf) {
        #pragma unroll
        for (int jt = 0; jt < 4; ++jt)
            #pragma unroll
            for (int r = 0; r < 4; ++r) {
                float h = fmaxf(acc[jt][r], 0.f);
                out_bf[(base + hi * 4 + r) * F + jt * 16 + lo] = f2bf(h);
            }
    } else {
        #pragma unroll
        for (int r = 0; r < 4; ++r) {
            float pr = 0.f, qr = 0.f;
            #pragma unroll
            for (int jt = 0; jt < 4; ++jt) {
                float h = fmaxf(acc[jt][r], 0.f);
                pr += h * w3n_s[jt];
                qr += h * w3s_s[jt];
            }
            #pragma unroll
            for (int off = 1; off < 16; off <<= 1) {
                pr += __shfl_xor(pr, off);
                qr += __shfl_xor(qr, off);
            }
            if (lo == 0) {
                pout[base + hi * 4 + r] = pr;
                qout[base + hi * 4 + r] = qr;
            }
        }
    }
}

// ---------------- final: out = q + mean_agg(p) + b3, 16 lanes per node ----------------

__global__ __launch_bounds__(256) void final_kernel(
        const int* __restrict__ row_beg, const unsigned short* __restrict__ degs,
        const unsigned short* __restrict__ csr16,
        const float* __restrict__ p, const float* __restrict__ q,
        const float* __restrict__ b3, float* __restrict__ out, int n_nodes) {
    int grp = threadIdx.x >> 4;
    int ln  = threadIdx.x & 15;
    int node = blockIdx.x * 16 + grp;
    if (node >= n_nodes) return;
    int beg = row_beg[node];
    int deg = degs[node];
    int end = beg + deg;
    float s = 0.f;
    for (int i = beg + ln; i < end; i += 16) s += p[csr16[i]];
    #pragma unroll
    for (int off = 1; off < 16; off <<= 1) s += __shfl_xor(s, off);
    if (ln == 0) {
        float inv = (deg > 0) ? (1.0f / (float)deg) : 0.f;
        out[node] = q[node] + s * inv + b3[0];
    }
}

// ---------------- launch ----------------

extern "C" void kernel_launch(void* const* d_in, const int* in_sizes, int n_in,
                              void* d_out, int out_size, void* d_ws, size_t ws_size,
                              hipStream_t stream) {
    const float* x   = (const float*)d_in[0];
    const int*   src = (const int*)d_in[1];
    const int*   dst = (const int*)d_in[2];
    const float* Ws1 = (const float*)d_in[3];
    const float* Wn1 = (const float*)d_in[4];
    const float* b1  = (const float*)d_in[5];
    const float* Ws2 = (const float*)d_in[6];
    const float* Wn2 = (const float*)d_in[7];
    const float* b2  = (const float*)d_in[8];
    const float* Ws3 = (const float*)d_in[9];
    const float* Wn3 = (const float*)d_in[10];
    const float* b3  = (const float*)d_in[11];
    float* out = (float*)d_out;

    char* ws = (char*)d_ws;
    size_t cur = 0;
    auto alloc = [&](size_t bytes) -> void* {
        void* p = ws + cur;
        cur += (bytes + 255) & ~(size_t)255;
        return p;
    };

    int*            bcur     = (int*)  alloc(NB * sizeof(int));
    unsigned int*   binned   = (unsigned int*)alloc((size_t)NB * BCAP * sizeof(unsigned int));
    int*            row_beg  = (int*)  alloc((size_t)(NB * BNODES) * sizeof(int));
    unsigned short* degs     = (unsigned short*)alloc((size_t)(NB * BNODES) * sizeof(unsigned short));
    unsigned short* csr16    = (unsigned short*)alloc((size_t)NB * BCAP * sizeof(unsigned short));
    unsigned short* xh       = (unsigned short*)alloc((size_t)N_NODES * F * 2);  // bf16 x
    unsigned short* h1h      = (unsigned short*)alloc((size_t)N_NODES * F * 2);  // bf16 h1
    unsigned short* aggh     = (unsigned short*)alloc((size_t)N_NODES * F * 2);  // bf16 agg
    unsigned short* Wt       = (unsigned short*)alloc(4 * F * F * 2);            // bf16 W^T x4
    float*          p        = (float*)alloc(N_NODES * sizeof(float));
    float*          q        = (float*)alloc(N_NODES * sizeof(float));

    unsigned short* Wst1 = Wt;
    unsigned short* Wnt1 = Wt + F * F;
    unsigned short* Wst2 = Wt + 2 * F * F;
    unsigned short* Wnt2 = Wt + 3 * F * F;

    // single-pass binned CSR build + prep (fused)
    (void)hipMemsetAsync(bcur, 0, NB * sizeof(int), stream);
    scatter_prep<<<SCAT_BLOCKS + PREP_BLOCKS, 512, 0, stream>>>(
        src, dst, bcur, binned,
        Ws1, Wn1, Ws2, Wn2, Wt, (const float4*)x, (ushort4*)xh);
    bucket_build<<<NB, 256, 0, stream>>>(binned, bcur, row_beg, degs, csr16);

    int agg_grid = (N_NODES + 3) / 4;
    int tf_grid  = (NTILES + 3) / 4;   // 782

    // layer 1
    aggregate_kernel<<<agg_grid, 256, 0, stream>>>(
        (const uint4*)xh, row_beg, degs, csr16, (uint4*)aggh, N_NODES);
    mfma_transform<<<tf_grid, 256, 0, stream>>>(
        (const uint4*)xh, (const uint4*)aggh, (const uint4*)Wst1, (const uint4*)Wnt1,
        b1, h1h, nullptr, nullptr, nullptr, nullptr, NTILES);
    // layer 2 (+ fused layer-3 projection)
    aggregate_kernel<<<agg_grid, 256, 0, stream>>>(
        (const uint4*)h1h, row_beg, degs, csr16, (uint4*)aggh, N_NODES);
    mfma_transform<<<tf_grid, 256, 0, stream>>>(
        (const uint4*)h1h, (const uint4*)aggh, (const uint4*)Wst2, (const uint4*)Wnt2,
        b2, nullptr, Ws3, Wn3, p, q, NTILES);
    // layer 3: aggregate scalars
    final_kernel<<<(N_NODES + 15) / 16, 256, 0, stream>>>(
        row_beg, degs, csr16, p, q, b3, out, N_NODES);
}